// Round 21
// baseline (166.280 us; speedup 1.0000x reference)
//
#include <hip/hip_runtime.h>

#define DIM    768
#define HEADS  12
#define HD     64
#define BB     4
#define PP     2048
#define MTOT   8192   /* BB*PP */
#define NQKV   2304
#define QBLK   128
#define KVBLK  128

typedef unsigned short bf16s;                                   // bf16 storage
typedef short bf16x8 __attribute__((ext_vector_type(8)));       // MFMA A/B frag
typedef float f32x4  __attribute__((ext_vector_type(4)));       // 16x16 C/D
typedef float f32x16 __attribute__((ext_vector_type(16)));      // 32x32 C/D

typedef const __attribute__((address_space(1))) unsigned int g_u32;
typedef __attribute__((address_space(3))) unsigned int lds_u32;

__device__ __forceinline__ bf16s f2bf(float f) {
    unsigned int u = __float_as_uint(f);
    unsigned int r = u + 0x7fffu + ((u >> 16) & 1u);            // RNE
    return (bf16s)(r >> 16);
}
__device__ __forceinline__ float bf2f(bf16s s) {
    return __uint_as_float(((unsigned int)s) << 16);
}
__device__ __forceinline__ float exp2g(float x) {
    return __builtin_amdgcn_exp2f(x);                           // v_exp_f32
}
__device__ __forceinline__ unsigned cvt_pk_bf16(float a, float b) {
    unsigned r;
    asm("v_cvt_pk_bf16_f32 %0, %1, %2" : "=v"(r) : "v"(a), "v"(b));
    return r;                                                   // lo=bf16(a), hi=bf16(b)
}
__device__ __forceinline__ float2 pk_add(float2 a, float2 b) {
    float2 r;
    asm("v_pk_add_f32 %0, %1, %2" : "=v"(r) : "v"(a), "v"(b));
    return r;
}

// ---------------------------------------------------------------- LayerNorm
// 192 threads/row, float4 loads, packed bf16 stores
__global__ __launch_bounds__(192) void ln_kernel(
        const float* __restrict__ x, const float* __restrict__ w,
        const float* __restrict__ b, bf16s* __restrict__ xn) {
    int row = blockIdx.x;
    const float* xr = x + (size_t)row * DIM;
    int t = threadIdx.x;
    float4 v = *(const float4*)&xr[t*4];
    float s  = (v.x + v.y) + (v.z + v.w);
    float ss = (v.x*v.x + v.y*v.y) + (v.z*v.z + v.w*v.w);
    for (int off = 32; off; off >>= 1) {
        s  += __shfl_down(s, off);
        ss += __shfl_down(ss, off);
    }
    __shared__ float red[8];
    int wid = t >> 6, lane = t & 63;
    if (lane == 0) { red[wid] = s; red[4 + wid] = ss; }
    __syncthreads();
    if (t == 0) {
        float S  = red[0] + red[1] + red[2];
        float SS = red[4] + red[5] + red[6];
        float mean = S * (1.0f / DIM);
        float var  = SS * (1.0f / DIM) - mean * mean;
        red[0] = mean;
        red[1] = rsqrtf(var + 1e-5f);
    }
    __syncthreads();
    float mean = red[0], inv = red[1];
    float4 wv = *(const float4*)&w[t*4];
    float4 bv = *(const float4*)&b[t*4];
    uint2 pk;
    pk.x = cvt_pk_bf16((v.x - mean) * inv * wv.x + bv.x,
                       (v.y - mean) * inv * wv.y + bv.y);
    pk.y = cvt_pk_bf16((v.z - mean) * inv * wv.z + bv.z,
                       (v.w - mean) * inv * wv.w + bv.w);
    *(uint2*)&xn[(size_t)row * DIM + t*4] = pk;
}

// ------------------------------------------------- transpose + cast weights
// one launch, grid.z selects: 0=Wq(*sc) 1=Wk 2=Wv -> Wqkv_t; 3=Wfc -> Wfc_h
__global__ __launch_bounds__(256) void transpose_all(
        const float* __restrict__ Wq, const float* __restrict__ Wk,
        const float* __restrict__ Wv, const float* __restrict__ Wfc,
        bf16s* __restrict__ Wqkv_t, bf16s* __restrict__ Wfc_h, float sc) {
    int z = blockIdx.z;
    const float* src = (z == 0) ? Wq : (z == 1) ? Wk : (z == 2) ? Wv : Wfc;
    float scale = (z == 0) ? sc : 1.0f;
    __shared__ float tile[32][33];
    int n0 = blockIdx.x * 32, k0 = blockIdx.y * 32;
    int tx = threadIdx.x, ty = threadIdx.y;
    #pragma unroll
    for (int i = 0; i < 4; ++i)
        tile[ty + 8*i][tx] = src[(size_t)(k0 + ty + 8*i) * DIM + n0 + tx];
    __syncthreads();
    #pragma unroll
    for (int i = 0; i < 4; ++i) {
        float v = tile[tx][ty + 8*i] * scale;
        size_t oidx = (size_t)(n0 + ty + 8*i) * DIM + k0 + tx;
        bf16s hi = f2bf(v);
        if (z < 3) Wqkv_t[(size_t)z * DIM * DIM + oidx] = hi;
        else       Wfc_h[oidx] = hi;
    }
}

// ----------------------------------------------------------------- GEMM
// C[M x N] = A[M x 768(K)] @ Bt[N x 768]^T ; 4 waves
// MODE 0: 128x128 tile (2x2 waves of 64x64), N=2304 -> Q/K [b,h,p,d], V^T (+bv)
// MODE 1: 128x64 tile (2x2 waves of 64x32), N=768, K=768, fp32 out + bfc
// Staging: global_load_lds width=16, linear LDS, source-XOR swizzle + read-XOR.
template<int MODE>
__global__ __launch_bounds__(256) void gemm_bt(
        const bf16s* __restrict__ A0, const bf16s* __restrict__ B0,
        const float* __restrict__ bias,
        bf16s* __restrict__ Qo, bf16s* __restrict__ Ko, bf16s* __restrict__ Vo,
        float* __restrict__ out) {
    const int BN   = (MODE == 0 ? 128 : 64);
    const int NI   = (MODE == 0 ? 4 : 2);             // B frags per wave
    const int BISS = (MODE == 0 ? 4 : 2);             // B staging issues
    const int NT   = (MODE == 0 ? NQKV / 128 : DIM / 64);
    const int NWG  = (MTOT / 128) * NT;
    int bid = blockIdx.x;
    bid = (bid & 7) * (NWG / 8) + (bid >> 3);         // XCD swizzle (NWG%8==0)
    int nt = bid % NT, mt = bid / NT;
    int m0 = mt * 128, n0 = nt * BN;
    __shared__ bf16s As[128 * 64];
    __shared__ bf16s Bs[BN * 64];
    int t = threadIdx.x;
    int lane = t & 63, w = t >> 6;
    int wr = w >> 1, wc = w & 1;
    int lr = lane & 15, lg = lane >> 4;
    // staging geometry: thread t, issue i covers LDS elems [i*2048+t*8, +8)
    int sflat[4];
    size_t sgoff[4];
    #pragma unroll
    for (int i = 0; i < 4; ++i) {
        int flat = i * 2048 + t * 8;
        int r = flat >> 6, c = flat & 63;
        int csw = (((c >> 3) ^ (r & 7)) << 3);        // source-side swizzle
        sflat[i] = flat;
        sgoff[i] = (size_t)r * DIM + csw;             // + m0/n0*DIM + k0 later
    }
    const int xorv = (lr & 7) << 3;                   // read-side XOR (elems)
    f32x4 acc[4][NI] = {};
    const int KI = DIM / 64;
    for (int it = 0; it < KI; ++it) {
        int k0 = it * 64;
        #pragma unroll
        for (int i = 0; i < 4; ++i)
            __builtin_amdgcn_global_load_lds(
                (g_u32*)(A0 + (size_t)m0 * DIM + k0 + sgoff[i]),
                (lds_u32*)&As[sflat[i]], 16, 0, 0);
        #pragma unroll
        for (int i = 0; i < BISS; ++i)
            __builtin_amdgcn_global_load_lds(
                (g_u32*)(B0 + (size_t)n0 * DIM + k0 + sgoff[i]),
                (lds_u32*)&Bs[sflat[i]], 16, 0, 0);
        __syncthreads();                               // vmcnt(0) drain + barrier
        #pragma unroll
        for (int kk = 0; kk < 2; ++kk) {
            bf16x8 af[4], bfr[NI];
            #pragma unroll
            for (int i = 0; i < 4; ++i) {
                int arow = wr*64 + i*16 + lr;
                af[i] = *(const bf16x8*)&As[arow*64 + ((kk*32 + lg*8) ^ xorv)];
            }
            #pragma unroll
            for (int i = 0; i < NI; ++i) {
                int brow = wc*(BN/2) + i*16 + lr;
                bfr[i] = *(const bf16x8*)&Bs[brow*64 + ((kk*32 + lg*8) ^ xorv)];
            }
            #pragma unroll
            for (int mi = 0; mi < 4; ++mi)
                #pragma unroll
                for (int ni = 0; ni < NI; ++ni)
                    acc[mi][ni] = __builtin_amdgcn_mfma_f32_16x16x32_bf16(
                        af[mi], bfr[ni], acc[mi][ni], 0, 0, 0);
        }
        __syncthreads();
    }
    if (MODE == 0) {
        #pragma unroll
        for (int mi = 0; mi < 4; ++mi) {
            int m_base = m0 + wr*64 + mi*16 + lg*4;
            int b = m_base >> 11, p = m_base & 2047;
            #pragma unroll
            for (int ni = 0; ni < NI; ++ni) {
                int n = n0 + wc*64 + ni*16 + lr;
                int which = n / DIM, within = n % DIM;
                int hh = within >> 6, d = within & 63;
                if (which == 2) {
                    float bb = bias[within];
                    uint2 pk;
                    pk.x = cvt_pk_bf16(acc[mi][ni][0] + bb, acc[mi][ni][1] + bb);
                    pk.y = cvt_pk_bf16(acc[mi][ni][2] + bb, acc[mi][ni][3] + bb);
                    *(uint2*)&Vo[(((size_t)(b*HEADS + hh))*HD + d)*PP + p] = pk;
                } else {
                    bf16s* dst = (which == 1) ? Ko : Qo;
                    #pragma unroll
                    for (int r = 0; r < 4; ++r)
                        dst[(((size_t)(b*HEADS + hh))*PP + p + r)*HD + d] =
                            f2bf(acc[mi][ni][r]);
                }
            }
        }
    } else {
        #pragma unroll
        for (int mi = 0; mi < 4; ++mi)
            #pragma unroll
            for (int ni = 0; ni < NI; ++ni)
                #pragma unroll
                for (int r = 0; r < 4; ++r) {
                    int m = m0 + wr*64 + mi*16 + lg*4 + r;
                    int n = n0 + wc*32 + ni*16 + lr;
                    out[(size_t)m * DIM + n] = acc[mi][ni][r] + bias[n];
                }
    }
}

// ------------------------------------------------------------ attention
// 32x32 MFMA structure (R15 template, KVBLK=128): block = (b,h,qtile-of-128).
// Swapped QK^T = mfma32(K, Q): C col=lane&31=q, row=crow(r,hi)=(r&3)+8(r>>2)+4hi.
// Softmax per-lane; pair-combine via shfl_xor 32; pk_add sum tree.
// P -> PV A-frags in-register: 32 cvt_pk + 16 v_permlane32_swap_b32.
// K/V via global_load_lds (linear LDS, src-XOR swizzle); 2-buffer dbuf,
// ONE __syncthreads per 128-kv iter (barrier count 31 -> 15).
__global__ __launch_bounds__(256, 2) void attn_kernel(
        const bf16s* __restrict__ Q, const bf16s* __restrict__ K,
        const bf16s* __restrict__ Vt,
        bf16s* __restrict__ Oh) {
    const int NWG = BB * HEADS * (PP / QBLK);        // 768
    int orig = blockIdx.x;
    int wg = (orig & 7) * (NWG / 8) + (orig >> 3);   // XCD swizzle
    int qt  = wg & 15;
    int tmp = wg >> 4;
    int h   = tmp % HEADS;
    int b   = tmp / HEADS;
    const size_t headoff = ((size_t)(b * HEADS + h)) * PP * HD;
    const bf16s* Qh = Q  + headoff;
    const bf16s* Kh = K  + headoff;
    const bf16s* Vh = Vt + headoff;                  // [d][p]
    __shared__ bf16s Ks[2][KVBLK * 64];              // [kv][d], swizzled
    __shared__ bf16s Vs[2][64 * KVBLK];              // [d][kv], swizzled
    int t = threadIdx.x, lane = t & 63, w = t >> 6;
    int l31 = lane & 31, hi = lane >> 5;
    int q0  = qt * QBLK;
    int qw0 = q0 + w * 32;                           // wave's 32 q rows
    const int xorv = (l31 & 7) << 3;                 // read-side XOR (elems)
    // Q fragments (B-operand): lane holds Q[qw0+l31][tt*16 + hi*8 + e]
    bf16x8 qf[4];
    #pragma unroll
    for (int tt = 0; tt < 4; ++tt)
        qf[tt] = *(const bf16x8*)&Qh[(size_t)(qw0 + l31) * HD + tt*16 + hi*8];
    float m_run = -1e30f, l_run = 0.f;
    f32x16 o32[2] = {};                              // O[q=crow(r,hi)][d=dt*32+l31]
    // staging geometry (per tile = 128x64 K elems + 64x128 V elems, 4 issues each)
    int sflat[4];
    size_t skoff[4], svoff[4];
    #pragma unroll
    for (int i = 0; i < 4; ++i) {
        int flat = i * 2048 + t * 8;
        sflat[i] = flat;
        {   // K: [kv r][d c], row len 64
            int r = flat >> 6, c = flat & 63;
            int csw = (((c >> 3) ^ (r & 7)) << 3);
            skoff[i] = (size_t)r * HD + csw;         // + j*KVBLK*HD per tile
        }
        {   // V: [d r][kv c], row len 128 (swizzle on chunk low-3 bits)
            int r = flat >> 7, c = flat & 127;
            int csw = ((c >> 3) ^ (r & 7)) << 3;     // c' = c ^ ((r&7)<<3)
            svoff[i] = (size_t)r * PP + ((c & ~127) | csw | (c & 0)) ;
            svoff[i] = (size_t)r * PP + (c ^ ((r & 7) << 3)); // explicit involution
        }
    }
    #pragma unroll
    for (int i = 0; i < 4; ++i) {
        __builtin_amdgcn_global_load_lds((g_u32*)(Kh + skoff[i]),
                                         (lds_u32*)&Ks[0][sflat[i]], 16, 0, 0);
        __builtin_amdgcn_global_load_lds((g_u32*)(Vh + svoff[i]),
                                         (lds_u32*)&Vs[0][sflat[i]], 16, 0, 0);
    }
    __syncthreads();
    const int NJ = PP / KVBLK;                       // 16
    for (int j = 0; j < NJ; ++j) {
        int cur = j & 1;
        if (j < NJ - 1) {                            // prefetch next tile -> LDS
            #pragma unroll
            for (int i = 0; i < 4; ++i) {
                __builtin_amdgcn_global_load_lds(
                    (g_u32*)(Kh + (size_t)(j+1)*KVBLK*HD + skoff[i]),
                    (lds_u32*)&Ks[cur ^ 1][sflat[i]], 16, 0, 0);
                __builtin_amdgcn_global_load_lds(
                    (g_u32*)(Vh + svoff[i] + (j+1)*KVBLK),
                    (lds_u32*)&Vs[cur ^ 1][sflat[i]], 16, 0, 0);
            }
        }
        // ---- QK^T: s[kt] = sum_t mfma32(K[kv=kt*32+l31][d], Q)  (exp2 domain)
        f32x16 s[4];
        #pragma unroll
        for (int kt = 0; kt < 4; ++kt) {
            f32x16 acc = {};
            #pragma unroll
            for (int tt = 0; tt < 4; ++tt) {
                bf16x8 kf = *(const bf16x8*)
                    &Ks[cur][(kt*32 + l31)*64 + ((tt*16 + hi*8) ^ xorv)];
                acc = __builtin_amdgcn_mfma_f32_32x32x16_bf16(
                    kf, qf[tt], acc, 0, 0, 0);
            }
            s[kt] = acc;
        }
        // ---- diagonal mask (wave-uniform trigger; static indices)
        if ((qw0 >> 7) == j) {
            int qrel = (qw0 & 127) + l31;            // lane's q within kv tile
            #pragma unroll
            for (int kt = 0; kt < 4; ++kt)
                #pragma unroll
                for (int r = 0; r < 16; ++r)
                    if (kt*32 + (r&3) + 8*(r>>2) + 4*hi == qrel)
                        s[kt][r] = -1e30f;
        }
        // ---- per-lane softmax over 64 values + pair-combine via lane^32
        float t0[8];
        #pragma unroll
        for (int i = 0; i < 8; ++i) {
            float a = fmaxf(fmaxf(s[0][2*i], s[0][2*i+1]),
                            fmaxf(s[1][2*i], s[1][2*i+1]));
            float c = fmaxf(fmaxf(s[2][2*i], s[2][2*i+1]),
                            fmaxf(s[3][2*i], s[3][2*i+1]));
            t0[i] = fmaxf(a, c);
        }
        float t1a = fmaxf(fmaxf(t0[0], t0[1]), fmaxf(t0[2], t0[3]));
        float t1b = fmaxf(fmaxf(t0[4], t0[5]), fmaxf(t0[6], t0[7]));
        float mt = fmaxf(t1a, t1b);
        mt = fmaxf(mt, __shfl_xor(mt, 32));
        if (!__all(mt <= m_run + 8.f)) {             // defer-max rescale (rare)
            float mn = fmaxf(m_run, mt);
            float corr = exp2g(m_run - mn);
            m_run = mn;
            l_run *= corr;
            #pragma unroll
            for (int r = 0; r < 16; ++r) {
                float cq = __shfl(corr, (r&3) + 8*(r>>2) + 4*hi);
                o32[0][r] *= cq;
                o32[1][r] *= cq;
            }
        }
        #pragma unroll
        for (int kt = 0; kt < 4; ++kt)
            #pragma unroll
            for (int r = 0; r < 16; ++r)
                s[kt][r] = exp2g(s[kt][r] - m_run);
        // packed-f32 sum tree
        float2 c0[8];
        #pragma unroll
        for (int i = 0; i < 8; ++i) {
            float2 a = pk_add(make_float2(s[0][2*i], s[0][2*i+1]),
                              make_float2(s[1][2*i], s[1][2*i+1]));
            float2 c = pk_add(make_float2(s[2][2*i], s[2][2*i+1]),
                              make_float2(s[3][2*i], s[3][2*i+1]));
            c0[i] = pk_add(a, c);
        }
        float2 d0 = pk_add(pk_add(c0[0], c0[1]), pk_add(c0[2], c0[3]));
        float2 d1 = pk_add(pk_add(c0[4], c0[5]), pk_add(c0[6], c0[7]));
        float2 e0 = pk_add(d0, d1);
        float rs = e0.x + e0.y;
        rs += __shfl_xor(rs, 32);
        l_run += rs;
        // ---- pack P into PV A-frags (in-register, per ks k-slot of 16 kv)
        #pragma unroll
        for (int ks = 0; ks < 8; ++ks) {
            const int kt = ks >> 1, rb = (ks & 1) * 8;
            unsigned x0 = cvt_pk_bf16(s[kt][rb+0], s[kt][rb+1]);
            unsigned x1 = cvt_pk_bf16(s[kt][rb+2], s[kt][rb+3]);
            unsigned y0 = cvt_pk_bf16(s[kt][rb+4], s[kt][rb+5]);
            unsigned y1 = cvt_pk_bf16(s[kt][rb+6], s[kt][rb+7]);
            asm("v_permlane32_swap_b32 %0, %1" : "+v"(x0), "+v"(y0));
            asm("v_permlane32_swap_b32 %0, %1" : "+v"(x1), "+v"(y1));
            uint4 pw;
            pw.x = x0; pw.y = x1; pw.z = y0; pw.w = y1;
            bf16x8 pa = __builtin_bit_cast(bf16x8, pw);
            #pragma unroll
            for (int dt = 0; dt < 2; ++dt) {
                bf16x8 vb = *(const bf16x8*)
                    &Vs[cur][(dt*32 + l31)*KVBLK + ((ks*16 + hi*8) ^ xorv)];
                o32[dt] = __builtin_amdgcn_mfma_f32_32x32x16_bf16(
                    pa, vb, o32[dt], 0, 0, 0);
            }
        }
        if (j < NJ - 1)
            __syncthreads();                         // drains prefetch + dbuf handoff
    }
    float inv = 1.0f / l_run;
    #pragma unroll
    for (int r = 0; r < 16; ++r) {
        int cr = (r&3) + 8*(r>>2) + 4*hi;
        float iv = __shfl(inv, cr);
        int q = qw0 + cr;
        #pragma unroll
        for (int dt = 0; dt < 2; ++dt) {
            int d = dt*32 + l31;
            size_t idx = ((size_t)b * PP + q) * DIM + h * HD + d;
            Oh[idx] = f2bf(o32[dt][r] * iv);
        }
    }
}

// ---------------------------------------------------------------- launch
extern "C" void kernel_launch(void* const* d_in, const int* in_sizes, int n_in,
                              void* d_out, int out_size, void* d_ws, size_t ws_size,
                              hipStream_t stream) {
    const float* x    = (const float*)d_in[0];
    const float* ln_w = (const float*)d_in[1];
    const float* ln_b = (const float*)d_in[2];
    const float* Wq   = (const float*)d_in[3];
    const float* Wk   = (const float*)d_in[4];
    const float* Wv   = (const float*)d_in[5];
    const float* bv   = (const float*)d_in[6];
    const float* Wfc  = (const float*)d_in[7];
    const float* bfc  = (const float*)d_in[8];
    float* out = (float*)d_out;

    char* ws = (char*)d_ws;
    size_t off = 0;
    auto alloc = [&](size_t bytes) {
        void* p = ws + off;
        off += (bytes + 255) & ~(size_t)255;
        return p;
    };
    bf16s* xn     = (bf16s*)alloc((size_t)MTOT * DIM * 2);
    bf16s* Wqkv_t = (bf16s*)alloc((size_t)NQKV * DIM * 2);
    bf16s* Wfc_h  = (bf16s*)alloc((size_t)DIM * DIM * 2);
    bf16s* Qb     = (bf16s*)alloc((size_t)MTOT * DIM * 2);
    bf16s* Kb     = (bf16s*)alloc((size_t)MTOT * DIM * 2);
    bf16s* Vtg    = (bf16s*)alloc((size_t)MTOT * DIM * 2);   // V^T [b,h,d,p]
    bf16s* Ah     = (bf16s*)alloc((size_t)MTOT * DIM * 2);

    const float SC = 0.125f * 1.44269504f;   // softmax scale * log2(e), folded into Wq

    ln_kernel<<<MTOT, 192, 0, stream>>>(x, ln_w, ln_b, xn);

    transpose_all<<<dim3(24, 24, 4), dim3(32, 8), 0, stream>>>(
        Wq, Wk, Wv, Wfc, Wqkv_t, Wfc_h, SC);

    gemm_bt<0><<<(MTOT / 128) * (NQKV / 128), 256, 0, stream>>>(
        xn, Wqkv_t, bv, Qb, Kb, Vtg, nullptr);

    attn_kernel<<<BB * HEADS * (PP / QBLK), 256, 0, stream>>>(Qb, Kb, Vtg, Ah);

    gemm_bt<1><<<(MTOT / 128) * (DIM / 64), 256, 0, stream>>>(
        Ah, Wfc_h, bfc, nullptr, nullptr, nullptr, out);
}

// Round 22
// 158.616 us; speedup vs baseline: 1.0483x; 1.0483x over previous
//
#include <hip/hip_runtime.h>

#define DIM    768
#define HEADS  12
#define HD     64
#define BB     4
#define PP     2048
#define MTOT   8192   /* BB*PP */
#define NQKV   2304
#define QBLK   128

typedef unsigned short bf16s;                                   // bf16 storage
typedef short bf16x8 __attribute__((ext_vector_type(8)));       // MFMA A/B frag
typedef float f32x4  __attribute__((ext_vector_type(4)));       // 16x16 C/D
typedef float f32x16 __attribute__((ext_vector_type(16)));      // 32x32 C/D

typedef const __attribute__((address_space(1))) unsigned int g_u32;
typedef __attribute__((address_space(3))) unsigned int lds_u32;

__device__ __forceinline__ bf16s f2bf(float f) {
    unsigned int u = __float_as_uint(f);
    unsigned int r = u + 0x7fffu + ((u >> 16) & 1u);            // RNE
    return (bf16s)(r >> 16);
}
__device__ __forceinline__ float bf2f(bf16s s) {
    return __uint_as_float(((unsigned int)s) << 16);
}
__device__ __forceinline__ float exp2g(float x) {
    return __builtin_amdgcn_exp2f(x);                           // v_exp_f32
}
__device__ __forceinline__ unsigned cvt_pk_bf16(float a, float b) {
    unsigned r;
    asm("v_cvt_pk_bf16_f32 %0, %1, %2" : "=v"(r) : "v"(a), "v"(b));
    return r;                                                   // lo=bf16(a), hi=bf16(b)
}
__device__ __forceinline__ float2 pk_add(float2 a, float2 b) {
    float2 r;
    asm("v_pk_add_f32 %0, %1, %2" : "=v"(r) : "v"(a), "v"(b));
    return r;
}

// ---------------------------------------------------------------- LayerNorm
// 192 threads/row, float4 loads, packed bf16 stores
__global__ __launch_bounds__(192) void ln_kernel(
        const float* __restrict__ x, const float* __restrict__ w,
        const float* __restrict__ b, bf16s* __restrict__ xn) {
    int row = blockIdx.x;
    const float* xr = x + (size_t)row * DIM;
    int t = threadIdx.x;
    float4 v = *(const float4*)&xr[t*4];
    float s  = (v.x + v.y) + (v.z + v.w);
    float ss = (v.x*v.x + v.y*v.y) + (v.z*v.z + v.w*v.w);
    for (int off = 32; off; off >>= 1) {
        s  += __shfl_down(s, off);
        ss += __shfl_down(ss, off);
    }
    __shared__ float red[8];
    int wid = t >> 6, lane = t & 63;
    if (lane == 0) { red[wid] = s; red[4 + wid] = ss; }
    __syncthreads();
    if (t == 0) {
        float S  = red[0] + red[1] + red[2];
        float SS = red[4] + red[5] + red[6];
        float mean = S * (1.0f / DIM);
        float var  = SS * (1.0f / DIM) - mean * mean;
        red[0] = mean;
        red[1] = rsqrtf(var + 1e-5f);
    }
    __syncthreads();
    float mean = red[0], inv = red[1];
    float4 wv = *(const float4*)&w[t*4];
    float4 bv = *(const float4*)&b[t*4];
    uint2 pk;
    pk.x = cvt_pk_bf16((v.x - mean) * inv * wv.x + bv.x,
                       (v.y - mean) * inv * wv.y + bv.y);
    pk.y = cvt_pk_bf16((v.z - mean) * inv * wv.z + bv.z,
                       (v.w - mean) * inv * wv.w + bv.w);
    *(uint2*)&xn[(size_t)row * DIM + t*4] = pk;
}

// ------------------------------------------------- transpose + cast weights
// one launch, grid.z selects: 0=Wq(*sc) 1=Wk 2=Wv -> Wqkv_t; 3=Wfc -> Wfc_h
__global__ __launch_bounds__(256) void transpose_all(
        const float* __restrict__ Wq, const float* __restrict__ Wk,
        const float* __restrict__ Wv, const float* __restrict__ Wfc,
        bf16s* __restrict__ Wqkv_t, bf16s* __restrict__ Wfc_h, float sc) {
    int z = blockIdx.z;
    const float* src = (z == 0) ? Wq : (z == 1) ? Wk : (z == 2) ? Wv : Wfc;
    float scale = (z == 0) ? sc : 1.0f;
    __shared__ float tile[32][33];
    int n0 = blockIdx.x * 32, k0 = blockIdx.y * 32;
    int tx = threadIdx.x, ty = threadIdx.y;
    #pragma unroll
    for (int i = 0; i < 4; ++i)
        tile[ty + 8*i][tx] = src[(size_t)(k0 + ty + 8*i) * DIM + n0 + tx];
    __syncthreads();
    #pragma unroll
    for (int i = 0; i < 4; ++i) {
        float v = tile[tx][ty + 8*i] * scale;
        size_t oidx = (size_t)(n0 + ty + 8*i) * DIM + k0 + tx;
        bf16s hi = f2bf(v);
        if (z < 3) Wqkv_t[(size_t)z * DIM * DIM + oidx] = hi;
        else       Wfc_h[oidx] = hi;
    }
}

// ----------------------------------------------------------------- GEMM
// C[M x N] = A[M x 768(K)] @ Bt[N x 768]^T ; 4 waves
// MODE 0: 128x128 tile (2x2 waves of 64x64), N=2304 -> Q/K [b,h,p,d], V^T (+bv)
// MODE 1: 128x64 tile (2x2 waves of 64x32), N=768, K=768, fp32 out + bfc
// Staging: global_load_lds width=16, linear LDS, source-XOR swizzle + read-XOR.
template<int MODE>
__global__ __launch_bounds__(256) void gemm_bt(
        const bf16s* __restrict__ A0, const bf16s* __restrict__ B0,
        const float* __restrict__ bias,
        bf16s* __restrict__ Qo, bf16s* __restrict__ Ko, bf16s* __restrict__ Vo,
        float* __restrict__ out) {
    const int BN   = (MODE == 0 ? 128 : 64);
    const int NI   = (MODE == 0 ? 4 : 2);             // B frags per wave
    const int BISS = (MODE == 0 ? 4 : 2);             // B staging issues
    const int NT   = (MODE == 0 ? NQKV / 128 : DIM / 64);
    const int NWG  = (MTOT / 128) * NT;
    int bid = blockIdx.x;
    bid = (bid & 7) * (NWG / 8) + (bid >> 3);         // XCD swizzle (NWG%8==0)
    int nt = bid % NT, mt = bid / NT;
    int m0 = mt * 128, n0 = nt * BN;
    __shared__ bf16s As[128 * 64];
    __shared__ bf16s Bs[BN * 64];
    int t = threadIdx.x;
    int lane = t & 63, w = t >> 6;
    int wr = w >> 1, wc = w & 1;
    int lr = lane & 15, lg = lane >> 4;
    // staging geometry: thread t, issue i covers LDS elems [i*2048+t*8, +8)
    int sflat[4];
    size_t sgoff[4];
    #pragma unroll
    for (int i = 0; i < 4; ++i) {
        int flat = i * 2048 + t * 8;
        int r = flat >> 6, c = flat & 63;
        int csw = (((c >> 3) ^ (r & 7)) << 3);        // source-side swizzle
        sflat[i] = flat;
        sgoff[i] = (size_t)r * DIM + csw;             // + m0/n0*DIM + k0 later
    }
    const int xorv = (lr & 7) << 3;                   // read-side XOR (elems)
    f32x4 acc[4][NI] = {};
    const int KI = DIM / 64;
    for (int it = 0; it < KI; ++it) {
        int k0 = it * 64;
        #pragma unroll
        for (int i = 0; i < 4; ++i)
            __builtin_amdgcn_global_load_lds(
                (g_u32*)(A0 + (size_t)m0 * DIM + k0 + sgoff[i]),
                (lds_u32*)&As[sflat[i]], 16, 0, 0);
        #pragma unroll
        for (int i = 0; i < BISS; ++i)
            __builtin_amdgcn_global_load_lds(
                (g_u32*)(B0 + (size_t)n0 * DIM + k0 + sgoff[i]),
                (lds_u32*)&Bs[sflat[i]], 16, 0, 0);
        __syncthreads();                               // vmcnt(0) drain + barrier
        #pragma unroll
        for (int kk = 0; kk < 2; ++kk) {
            bf16x8 af[4], bfr[NI];
            #pragma unroll
            for (int i = 0; i < 4; ++i) {
                int arow = wr*64 + i*16 + lr;
                af[i] = *(const bf16x8*)&As[arow*64 + ((kk*32 + lg*8) ^ xorv)];
            }
            #pragma unroll
            for (int i = 0; i < NI; ++i) {
                int brow = wc*(BN/2) + i*16 + lr;
                bfr[i] = *(const bf16x8*)&Bs[brow*64 + ((kk*32 + lg*8) ^ xorv)];
            }
            #pragma unroll
            for (int mi = 0; mi < 4; ++mi)
                #pragma unroll
                for (int ni = 0; ni < NI; ++ni)
                    acc[mi][ni] = __builtin_amdgcn_mfma_f32_16x16x32_bf16(
                        af[mi], bfr[ni], acc[mi][ni], 0, 0, 0);
        }
        __syncthreads();
    }
    if (MODE == 0) {
        #pragma unroll
        for (int mi = 0; mi < 4; ++mi) {
            int m_base = m0 + wr*64 + mi*16 + lg*4;
            int b = m_base >> 11, p = m_base & 2047;
            #pragma unroll
            for (int ni = 0; ni < NI; ++ni) {
                int n = n0 + wc*64 + ni*16 + lr;
                int which = n / DIM, within = n % DIM;
                int hh = within >> 6, d = within & 63;
                if (which == 2) {
                    float bb = bias[within];
                    uint2 pk;
                    pk.x = cvt_pk_bf16(acc[mi][ni][0] + bb, acc[mi][ni][1] + bb);
                    pk.y = cvt_pk_bf16(acc[mi][ni][2] + bb, acc[mi][ni][3] + bb);
                    *(uint2*)&Vo[(((size_t)(b*HEADS + hh))*HD + d)*PP + p] = pk;
                } else {
                    bf16s* dst = (which == 1) ? Ko : Qo;
                    #pragma unroll
                    for (int r = 0; r < 4; ++r)
                        dst[(((size_t)(b*HEADS + hh))*PP + p + r)*HD + d] =
                            f2bf(acc[mi][ni][r]);
                }
            }
        }
    } else {
        #pragma unroll
        for (int mi = 0; mi < 4; ++mi)
            #pragma unroll
            for (int ni = 0; ni < NI; ++ni)
                #pragma unroll
                for (int r = 0; r < 4; ++r) {
                    int m = m0 + wr*64 + mi*16 + lg*4 + r;
                    int n = n0 + wc*32 + ni*16 + lr;
                    out[(size_t)m * DIM + n] = acc[mi][ni][r] + bias[n];
                }
    }
}

// ------------------------------------------------------------ attention
// 32x32 MFMA structure (R15/R20-proven): block = (b,h,qtile-of-128); 4 waves.
// Swapped QK^T = mfma32(K, Q): C col=lane&31=q, row=crow(r,hi)=(r&3)+8(r>>2)+4hi.
// Softmax per-lane; pair-combine via shfl_xor 32; pk_add sum tree.
// P -> PV A-frags in-register: 16 cvt_pk + 8 v_permlane32_swap_b32.
// K/V via global_load_lds (linear LDS, src-XOR swizzle); 2-buffer dbuf,
// ONE __syncthreads per 64-kv iter. Output: single bf16.
__global__ __launch_bounds__(256, 3) void attn_kernel(
        const bf16s* __restrict__ Q, const bf16s* __restrict__ K,
        const bf16s* __restrict__ Vt,
        bf16s* __restrict__ Oh) {
    const int NWG = BB * HEADS * (PP / QBLK);        // 768
    int orig = blockIdx.x;
    int wg = (orig & 7) * (NWG / 8) + (orig >> 3);   // XCD swizzle
    int qt  = wg & 15;
    int tmp = wg >> 4;
    int h   = tmp % HEADS;
    int b   = tmp / HEADS;
    const size_t headoff = ((size_t)(b * HEADS + h)) * PP * HD;
    const bf16s* Qh = Q  + headoff;
    const bf16s* Kh = K  + headoff;
    const bf16s* Vh = Vt + headoff;                  // [d][p]
    __shared__ bf16s Ks[2][64 * 64];                 // [kv][d], swizzled
    __shared__ bf16s Vs[2][64 * 64];                 // [d][kv], swizzled
    int t = threadIdx.x, lane = t & 63, w = t >> 6;
    int l31 = lane & 31, hi = lane >> 5;
    int q0  = qt * QBLK;
    int qw0 = q0 + w * 32;                           // wave's 32 q rows
    const int xorv = (l31 & 7) << 3;                 // read-side XOR (elems)
    // Q fragments (B-operand): lane holds Q[qw0+l31][tt*16 + hi*8 + e]
    bf16x8 qf[4];
    #pragma unroll
    for (int tt = 0; tt < 4; ++tt)
        qf[tt] = *(const bf16x8*)&Qh[(size_t)(qw0 + l31) * HD + tt*16 + hi*8];
    float m_run = -1e30f, l_run = 0.f;
    f32x16 o32[2] = {};                              // O[q=crow(r,hi)][d=dt*32+l31]
    // staging geometry: thread t, issue i covers LDS elems [i*2048+t*8, +8)
    int sflat[2];
    size_t skoff[2], svoff[2];
    #pragma unroll
    for (int i = 0; i < 2; ++i) {
        int flat = i * 2048 + t * 8;
        int r = flat >> 6, c = flat & 63;
        int csw = (((c >> 3) ^ (r & 7)) << 3);       // source-side swizzle
        sflat[i] = flat;
        skoff[i] = (size_t)r * HD + csw;             // + j*64*HD per tile
        svoff[i] = (size_t)r * PP + csw;             // + j*64 per tile
    }
    #pragma unroll
    for (int i = 0; i < 2; ++i) {
        __builtin_amdgcn_global_load_lds((g_u32*)(Kh + skoff[i]),
                                         (lds_u32*)&Ks[0][sflat[i]], 16, 0, 0);
        __builtin_amdgcn_global_load_lds((g_u32*)(Vh + svoff[i]),
                                         (lds_u32*)&Vs[0][sflat[i]], 16, 0, 0);
    }
    __syncthreads();
    for (int j = 0; j < 32; ++j) {
        int cur = j & 1;
        if (j < 31) {                                // prefetch next tile -> LDS
            #pragma unroll
            for (int i = 0; i < 2; ++i) {
                __builtin_amdgcn_global_load_lds(
                    (g_u32*)(Kh + (size_t)(j+1)*64*HD + skoff[i]),
                    (lds_u32*)&Ks[cur ^ 1][sflat[i]], 16, 0, 0);
                __builtin_amdgcn_global_load_lds(
                    (g_u32*)(Vh + svoff[i] + (j+1)*64),
                    (lds_u32*)&Vs[cur ^ 1][sflat[i]], 16, 0, 0);
            }
        }
        // ---- QK^T: s[kt] = sum_t mfma32(K[kv=kt*32+l31][d], Q)  (exp2 domain)
        f32x16 s[2] = {};
        #pragma unroll
        for (int kt = 0; kt < 2; ++kt) {
            #pragma unroll
            for (int tt = 0; tt < 4; ++tt) {
                bf16x8 kf = *(const bf16x8*)
                    &Ks[cur][(kt*32 + l31)*64 + ((tt*16 + hi*8) ^ xorv)];
                s[kt] = __builtin_amdgcn_mfma_f32_32x32x16_bf16(
                    kf, qf[tt], s[kt], 0, 0, 0);
            }
        }
        // ---- diagonal mask (wave-uniform trigger; static indices)
        if ((qw0 >> 6) == j) {
            int qrel = (qw0 & 63) + l31;             // lane's q within kv tile
            #pragma unroll
            for (int kt = 0; kt < 2; ++kt)
                #pragma unroll
                for (int r = 0; r < 16; ++r)
                    if (kt*32 + (r&3) + 8*(r>>2) + 4*hi == qrel)
                        s[kt][r] = -1e30f;
        }
        // ---- per-lane softmax over 32 values + pair-combine via lane^32
        float t0[8];
        #pragma unroll
        for (int i = 0; i < 8; ++i)
            t0[i] = fmaxf(fmaxf(s[0][2*i], s[0][2*i+1]),
                          fmaxf(s[1][2*i], s[1][2*i+1]));
        float t1a = fmaxf(fmaxf(t0[0], t0[1]), fmaxf(t0[2], t0[3]));
        float t1b = fmaxf(fmaxf(t0[4], t0[5]), fmaxf(t0[6], t0[7]));
        float mt = fmaxf(t1a, t1b);
        mt = fmaxf(mt, __shfl_xor(mt, 32));
        if (!__all(mt <= m_run + 8.f)) {             // defer-max rescale (rare)
            float mn = fmaxf(m_run, mt);
            float corr = exp2g(m_run - mn);
            m_run = mn;
            l_run *= corr;
            #pragma unroll
            for (int r = 0; r < 16; ++r) {
                float cq = __shfl(corr, (r&3) + 8*(r>>2) + 4*hi);
                o32[0][r] *= cq;
                o32[1][r] *= cq;
            }
        }
        #pragma unroll
        for (int kt = 0; kt < 2; ++kt)
            #pragma unroll
            for (int r = 0; r < 16; ++r)
                s[kt][r] = exp2g(s[kt][r] - m_run);
        // packed-f32 sum tree: 15 v_pk_add_f32 + 1 scalar
        float2 c0[8];
        #pragma unroll
        for (int i = 0; i < 8; ++i)
            c0[i] = pk_add(make_float2(s[0][2*i], s[0][2*i+1]),
                           make_float2(s[1][2*i], s[1][2*i+1]));
        float2 d0 = pk_add(pk_add(c0[0], c0[1]), pk_add(c0[2], c0[3]));
        float2 d1 = pk_add(pk_add(c0[4], c0[5]), pk_add(c0[6], c0[7]));
        float2 e0 = pk_add(d0, d1);
        float rs = e0.x + e0.y;
        rs += __shfl_xor(rs, 32);
        l_run += rs;
        // ---- pack P into PV A-frags (in-register, per ks k-slot of 16 kv)
        #pragma unroll
        for (int ks = 0; ks < 4; ++ks) {
            const int kt = ks >> 1, rb = (ks & 1) * 8;
            unsigned x0 = cvt_pk_bf16(s[kt][rb+0], s[kt][rb+1]);
            unsigned x1 = cvt_pk_bf16(s[kt][rb+2], s[kt][rb+3]);
            unsigned y0 = cvt_pk_bf16(s[kt][rb+4], s[kt][rb+5]);
            unsigned y1 = cvt_pk_bf16(s[kt][rb+6], s[kt][rb+7]);
            asm("v_permlane32_swap_b32 %0, %1" : "+v"(x0), "+v"(y0));
            asm("v_permlane32_swap_b32 %0, %1" : "+v"(x1), "+v"(y1));
            uint4 pw;
            pw.x = x0; pw.y = x1; pw.z = y0; pw.w = y1;
            bf16x8 pa = __builtin_bit_cast(bf16x8, pw);
            #pragma unroll
            for (int dt = 0; dt < 2; ++dt) {
                bf16x8 vb = *(const bf16x8*)
                    &Vs[cur][(dt*32 + l31)*64 + ((ks*16 + hi*8) ^ xorv)];
                o32[dt] = __builtin_amdgcn_mfma_f32_32x32x16_bf16(
                    pa, vb, o32[dt], 0, 0, 0);
            }
        }
        if (j < 31)
            __syncthreads();                         // drains prefetch + dbuf handoff
    }
    float inv = 1.0f / l_run;
    #pragma unroll
    for (int r = 0; r < 16; ++r) {
        int cr = (r&3) + 8*(r>>2) + 4*hi;
        float iv = __shfl(inv, cr);
        int q = qw0 + cr;
        #pragma unroll
        for (int dt = 0; dt < 2; ++dt) {
            int d = dt*32 + l31;
            size_t idx = ((size_t)b * PP + q) * DIM + h * HD + d;
            Oh[idx] = f2bf(o32[dt][r] * iv);
        }
    }
}

// ---------------------------------------------------------------- launch
extern "C" void kernel_launch(void* const* d_in, const int* in_sizes, int n_in,
                              void* d_out, int out_size, void* d_ws, size_t ws_size,
                              hipStream_t stream) {
    const float* x    = (const float*)d_in[0];
    const float* ln_w = (const float*)d_in[1];
    const float* ln_b = (const float*)d_in[2];
    const float* Wq   = (const float*)d_in[3];
    const float* Wk   = (const float*)d_in[4];
    const float* Wv   = (const float*)d_in[5];
    const float* bv   = (const float*)d_in[6];
    const float* Wfc  = (const float*)d_in[7];
    const float* bfc  = (const float*)d_in[8];
    float* out = (float*)d_out;

    char* ws = (char*)d_ws;
    size_t off = 0;
    auto alloc = [&](size_t bytes) {
        void* p = ws + off;
        off += (bytes + 255) & ~(size_t)255;
        return p;
    };
    bf16s* xn     = (bf16s*)alloc((size_t)MTOT * DIM * 2);
    bf16s* Wqkv_t = (bf16s*)alloc((size_t)NQKV * DIM * 2);
    bf16s* Wfc_h  = (bf16s*)alloc((size_t)DIM * DIM * 2);
    bf16s* Qb     = (bf16s*)alloc((size_t)MTOT * DIM * 2);
    bf16s* Kb     = (bf16s*)alloc((size_t)MTOT * DIM * 2);
    bf16s* Vtg    = (bf16s*)alloc((size_t)MTOT * DIM * 2);   // V^T [b,h,d,p]
    bf16s* Ah     = (bf16s*)alloc((size_t)MTOT * DIM * 2);

    const float SC = 0.125f * 1.44269504f;   // softmax scale * log2(e), folded into Wq

    ln_kernel<<<MTOT, 192, 0, stream>>>(x, ln_w, ln_b, xn);

    transpose_all<<<dim3(24, 24, 4), dim3(32, 8), 0, stream>>>(
        Wq, Wk, Wv, Wfc, Wqkv_t, Wfc_h, SC);

    gemm_bt<0><<<(MTOT / 128) * (NQKV / 128), 256, 0, stream>>>(
        xn, Wqkv_t, bv, Qb, Kb, Vtg, nullptr);

    attn_kernel<<<BB * HEADS * (PP / QBLK), 256, 0, stream>>>(Qb, Kb, Vtg, Ah);

    gemm_bt<1><<<(MTOT / 128) * (DIM / 64), 256, 0, stream>>>(
        Ah, Wfc_h, bfc, nullptr, nullptr, nullptr, out);
}

// Round 23
// 156.437 us; speedup vs baseline: 1.0629x; 1.0139x over previous
//
#include <hip/hip_runtime.h>

#define DIM    768
#define HEADS  12
#define HD     64
#define BB     4
#define PP     2048
#define MTOT   8192   /* BB*PP */
#define NQKV   2304
#define QBLK   128

typedef unsigned short bf16s;                                   // bf16 storage
typedef short bf16x8 __attribute__((ext_vector_type(8)));       // MFMA A/B frag
typedef float f32x4  __attribute__((ext_vector_type(4)));       // 16x16 C/D
typedef float f32x16 __attribute__((ext_vector_type(16)));      // 32x32 C/D

typedef const __attribute__((address_space(1))) unsigned int g_u32;
typedef __attribute__((address_space(3))) unsigned int lds_u32;

__device__ __forceinline__ bf16s f2bf(float f) {
    unsigned int u = __float_as_uint(f);
    unsigned int r = u + 0x7fffu + ((u >> 16) & 1u);            // RNE
    return (bf16s)(r >> 16);
}
__device__ __forceinline__ float bf2f(bf16s s) {
    return __uint_as_float(((unsigned int)s) << 16);
}
__device__ __forceinline__ float exp2g(float x) {
    return __builtin_amdgcn_exp2f(x);                           // v_exp_f32
}
__device__ __forceinline__ unsigned cvt_pk_bf16(float a, float b) {
    unsigned r;
    asm("v_cvt_pk_bf16_f32 %0, %1, %2" : "=v"(r) : "v"(a), "v"(b));
    return r;                                                   // lo=bf16(a), hi=bf16(b)
}
__device__ __forceinline__ float2 pk_add(float2 a, float2 b) {
    float2 r;
    asm("v_pk_add_f32 %0, %1, %2" : "=v"(r) : "v"(a), "v"(b));
    return r;
}

// ---------------------------------------------------------------- LayerNorm
// 192 threads/row, float4 loads, packed bf16 stores
__global__ __launch_bounds__(192) void ln_kernel(
        const float* __restrict__ x, const float* __restrict__ w,
        const float* __restrict__ b, bf16s* __restrict__ xn) {
    int row = blockIdx.x;
    const float* xr = x + (size_t)row * DIM;
    int t = threadIdx.x;
    float4 v = *(const float4*)&xr[t*4];
    float s  = (v.x + v.y) + (v.z + v.w);
    float ss = (v.x*v.x + v.y*v.y) + (v.z*v.z + v.w*v.w);
    for (int off = 32; off; off >>= 1) {
        s  += __shfl_down(s, off);
        ss += __shfl_down(ss, off);
    }
    __shared__ float red[8];
    int wid = t >> 6, lane = t & 63;
    if (lane == 0) { red[wid] = s; red[4 + wid] = ss; }
    __syncthreads();
    if (t == 0) {
        float S  = red[0] + red[1] + red[2];
        float SS = red[4] + red[5] + red[6];
        float mean = S * (1.0f / DIM);
        float var  = SS * (1.0f / DIM) - mean * mean;
        red[0] = mean;
        red[1] = rsqrtf(var + 1e-5f);
    }
    __syncthreads();
    float mean = red[0], inv = red[1];
    float4 wv = *(const float4*)&w[t*4];
    float4 bv = *(const float4*)&b[t*4];
    uint2 pk;
    pk.x = cvt_pk_bf16((v.x - mean) * inv * wv.x + bv.x,
                       (v.y - mean) * inv * wv.y + bv.y);
    pk.y = cvt_pk_bf16((v.z - mean) * inv * wv.z + bv.z,
                       (v.w - mean) * inv * wv.w + bv.w);
    *(uint2*)&xn[(size_t)row * DIM + t*4] = pk;
}

// ------------------------------------------------- transpose + cast weights
// one launch, grid.z selects: 0=Wq(*sc) 1=Wk 2=Wv -> Wqkv_t; 3=Wfc -> Wfc_h
__global__ __launch_bounds__(256) void transpose_all(
        const float* __restrict__ Wq, const float* __restrict__ Wk,
        const float* __restrict__ Wv, const float* __restrict__ Wfc,
        bf16s* __restrict__ Wqkv_t, bf16s* __restrict__ Wfc_h, float sc) {
    int z = blockIdx.z;
    const float* src = (z == 0) ? Wq : (z == 1) ? Wk : (z == 2) ? Wv : Wfc;
    float scale = (z == 0) ? sc : 1.0f;
    __shared__ float tile[32][33];
    int n0 = blockIdx.x * 32, k0 = blockIdx.y * 32;
    int tx = threadIdx.x, ty = threadIdx.y;
    #pragma unroll
    for (int i = 0; i < 4; ++i)
        tile[ty + 8*i][tx] = src[(size_t)(k0 + ty + 8*i) * DIM + n0 + tx];
    __syncthreads();
    #pragma unroll
    for (int i = 0; i < 4; ++i) {
        float v = tile[tx][ty + 8*i] * scale;
        size_t oidx = (size_t)(n0 + ty + 8*i) * DIM + k0 + tx;
        bf16s hi = f2bf(v);
        if (z < 3) Wqkv_t[(size_t)z * DIM * DIM + oidx] = hi;
        else       Wfc_h[oidx] = hi;
    }
}

// ----------------------------------------------------------------- GEMM
// C[M x N] = A[M x 768(K)] @ Bt[N x 768]^T ; 4 waves
// MODE 0: 128x128 tile, N=2304. Q/K region: SWAPPED operands (acc = C^T) so
//   each lane holds 4 d-consecutive values -> packed uint2 [p][d] stores.
//   V region: unswapped, packed V^T [d][p] stores (+bv).
// MODE 1: 128x64 tile, N=768, K=768, fp32 out + bfc
// Staging: global_load_lds width=16, linear LDS, source-XOR swizzle + read-XOR.
template<int MODE>
__global__ __launch_bounds__(256) void gemm_bt(
        const bf16s* __restrict__ A0, const bf16s* __restrict__ B0,
        const float* __restrict__ bias,
        bf16s* __restrict__ Qo, bf16s* __restrict__ Ko, bf16s* __restrict__ Vo,
        float* __restrict__ out) {
    const int BN   = (MODE == 0 ? 128 : 64);
    const int NI   = (MODE == 0 ? 4 : 2);             // B frags per wave
    const int BISS = (MODE == 0 ? 4 : 2);             // B staging issues
    const int NT   = (MODE == 0 ? NQKV / 128 : DIM / 64);
    const int NWG  = (MTOT / 128) * NT;
    int bid = blockIdx.x;
    bid = (bid & 7) * (NWG / 8) + (bid >> 3);         // XCD swizzle (NWG%8==0)
    int nt = bid % NT, mt = bid / NT;
    int m0 = mt * 128, n0 = nt * BN;
    __shared__ bf16s As[128 * 64];
    __shared__ bf16s Bs[BN * 64];
    int t = threadIdx.x;
    int lane = t & 63, w = t >> 6;
    int wr = w >> 1, wc = w & 1;
    int lr = lane & 15, lg = lane >> 4;
    const bool swp = (MODE == 0) && (n0 < 2 * DIM);   // Q/K region: C^T layout
    // staging geometry: thread t, issue i covers LDS elems [i*2048+t*8, +8)
    int sflat[4];
    size_t sgoff[4];
    #pragma unroll
    for (int i = 0; i < 4; ++i) {
        int flat = i * 2048 + t * 8;
        int r = flat >> 6, c = flat & 63;
        int csw = (((c >> 3) ^ (r & 7)) << 3);        // source-side swizzle
        sflat[i] = flat;
        sgoff[i] = (size_t)r * DIM + csw;             // + m0/n0*DIM + k0 later
    }
    const int xorv = (lr & 7) << 3;                   // read-side XOR (elems)
    f32x4 acc[4][NI] = {};
    const int KI = DIM / 64;
    for (int it = 0; it < KI; ++it) {
        int k0 = it * 64;
        #pragma unroll
        for (int i = 0; i < 4; ++i)
            __builtin_amdgcn_global_load_lds(
                (g_u32*)(A0 + (size_t)m0 * DIM + k0 + sgoff[i]),
                (lds_u32*)&As[sflat[i]], 16, 0, 0);
        #pragma unroll
        for (int i = 0; i < BISS; ++i)
            __builtin_amdgcn_global_load_lds(
                (g_u32*)(B0 + (size_t)n0 * DIM + k0 + sgoff[i]),
                (lds_u32*)&Bs[sflat[i]], 16, 0, 0);
        __syncthreads();                               // vmcnt(0) drain + barrier
        #pragma unroll
        for (int kk = 0; kk < 2; ++kk) {
            bf16x8 af[4], bfr[NI];
            #pragma unroll
            for (int i = 0; i < 4; ++i) {
                int arow = wr*64 + i*16 + lr;
                af[i] = *(const bf16x8*)&As[arow*64 + ((kk*32 + lg*8) ^ xorv)];
            }
            #pragma unroll
            for (int i = 0; i < NI; ++i) {
                int brow = wc*(BN/2) + i*16 + lr;
                bfr[i] = *(const bf16x8*)&Bs[brow*64 + ((kk*32 + lg*8) ^ xorv)];
            }
            if (swp) {                                 // block-uniform branch
                #pragma unroll
                for (int mi = 0; mi < 4; ++mi)
                    #pragma unroll
                    for (int ni = 0; ni < NI; ++ni)
                        acc[mi][ni] = __builtin_amdgcn_mfma_f32_16x16x32_bf16(
                            bfr[ni], af[mi], acc[mi][ni], 0, 0, 0);
            } else {
                #pragma unroll
                for (int mi = 0; mi < 4; ++mi)
                    #pragma unroll
                    for (int ni = 0; ni < NI; ++ni)
                        acc[mi][ni] = __builtin_amdgcn_mfma_f32_16x16x32_bf16(
                            af[mi], bfr[ni], acc[mi][ni], 0, 0, 0);
            }
        }
        __syncthreads();
    }
    if (MODE == 0) {
        if (swp) {
            // C^T: lane holds m = ...+lr (fixed), n = ...+lg*4+r (4 consecutive d)
            bf16s* dst = (n0 >= DIM) ? Ko : Qo;
            int nbase = n0 - ((n0 >= DIM) ? DIM : 0);
            #pragma unroll
            for (int mi = 0; mi < 4; ++mi) {
                int m = m0 + wr*64 + mi*16 + lr;
                int b = m >> 11, p = m & 2047;
                #pragma unroll
                for (int ni = 0; ni < NI; ++ni) {
                    int nb = nbase + wc*64 + ni*16 + lg*4;
                    int hh = nb >> 6, d0 = nb & 63;
                    uint2 pk;
                    pk.x = cvt_pk_bf16(acc[mi][ni][0], acc[mi][ni][1]);
                    pk.y = cvt_pk_bf16(acc[mi][ni][2], acc[mi][ni][3]);
                    *(uint2*)&dst[(((size_t)(b*HEADS + hh))*PP + p)*HD + d0] = pk;
                }
            }
        } else {
            // V region: lane holds n = ...+lr (fixed d), m = ...+lg*4+r (4 consec p)
            #pragma unroll
            for (int mi = 0; mi < 4; ++mi) {
                int m_base = m0 + wr*64 + mi*16 + lg*4;
                int b = m_base >> 11, p = m_base & 2047;
                #pragma unroll
                for (int ni = 0; ni < NI; ++ni) {
                    int n = n0 + wc*64 + ni*16 + lr;
                    int within = n - 2*DIM;
                    int hh = within >> 6, d = within & 63;
                    float bb = bias[within];
                    uint2 pk;
                    pk.x = cvt_pk_bf16(acc[mi][ni][0] + bb, acc[mi][ni][1] + bb);
                    pk.y = cvt_pk_bf16(acc[mi][ni][2] + bb, acc[mi][ni][3] + bb);
                    *(uint2*)&Vo[(((size_t)(b*HEADS + hh))*HD + d)*PP + p] = pk;
                }
            }
        }
    } else {
        #pragma unroll
        for (int mi = 0; mi < 4; ++mi)
            #pragma unroll
            for (int ni = 0; ni < NI; ++ni)
                #pragma unroll
                for (int r = 0; r < 4; ++r) {
                    int m = m0 + wr*64 + mi*16 + lg*4 + r;
                    int n = n0 + wc*32 + ni*16 + lr;
                    out[(size_t)m * DIM + n] = acc[mi][ni][r] + bias[n];
                }
    }
}

// ------------------------------------------------------------ attention
// 32x32 MFMA structure (R15/R20-proven): block = (b,h,qtile-of-128); 4 waves.
// Swapped QK^T = mfma32(K, Q): C col=lane&31=q, row=crow(r,hi)=(r&3)+8(r>>2)+4hi.
// Softmax per-lane; pair-combine via shfl_xor 32; pk_add sum tree.
// P -> PV A-frags in-register: 16 cvt_pk + 8 v_permlane32_swap_b32.
// K/V via global_load_lds (linear LDS, src-XOR swizzle); 2-buffer dbuf,
// ONE __syncthreads per 64-kv iter. Output: single bf16.
__global__ __launch_bounds__(256, 3) void attn_kernel(
        const bf16s* __restrict__ Q, const bf16s* __restrict__ K,
        const bf16s* __restrict__ Vt,
        bf16s* __restrict__ Oh) {
    const int NWG = BB * HEADS * (PP / QBLK);        // 768
    int orig = blockIdx.x;
    int wg = (orig & 7) * (NWG / 8) + (orig >> 3);   // XCD swizzle
    int qt  = wg & 15;
    int tmp = wg >> 4;
    int h   = tmp % HEADS;
    int b   = tmp / HEADS;
    const size_t headoff = ((size_t)(b * HEADS + h)) * PP * HD;
    const bf16s* Qh = Q  + headoff;
    const bf16s* Kh = K  + headoff;
    const bf16s* Vh = Vt + headoff;                  // [d][p]
    __shared__ bf16s Ks[2][64 * 64];                 // [kv][d], swizzled
    __shared__ bf16s Vs[2][64 * 64];                 // [d][kv], swizzled
    int t = threadIdx.x, lane = t & 63, w = t >> 6;
    int l31 = lane & 31, hi = lane >> 5;
    int q0  = qt * QBLK;
    int qw0 = q0 + w * 32;                           // wave's 32 q rows
    const int xorv = (l31 & 7) << 3;                 // read-side XOR (elems)
    // Q fragments (B-operand): lane holds Q[qw0+l31][tt*16 + hi*8 + e]
    bf16x8 qf[4];
    #pragma unroll
    for (int tt = 0; tt < 4; ++tt)
        qf[tt] = *(const bf16x8*)&Qh[(size_t)(qw0 + l31) * HD + tt*16 + hi*8];
    float m_run = -1e30f, l_run = 0.f;
    f32x16 o32[2] = {};                              // O[q=crow(r,hi)][d=dt*32+l31]
    // staging geometry: thread t, issue i covers LDS elems [i*2048+t*8, +8)
    int sflat[2];
    size_t skoff[2], svoff[2];
    #pragma unroll
    for (int i = 0; i < 2; ++i) {
        int flat = i * 2048 + t * 8;
        int r = flat >> 6, c = flat & 63;
        int csw = (((c >> 3) ^ (r & 7)) << 3);       // source-side swizzle
        sflat[i] = flat;
        skoff[i] = (size_t)r * HD + csw;             // + j*64*HD per tile
        svoff[i] = (size_t)r * PP + csw;             // + j*64 per tile
    }
    #pragma unroll
    for (int i = 0; i < 2; ++i) {
        __builtin_amdgcn_global_load_lds((g_u32*)(Kh + skoff[i]),
                                         (lds_u32*)&Ks[0][sflat[i]], 16, 0, 0);
        __builtin_amdgcn_global_load_lds((g_u32*)(Vh + svoff[i]),
                                         (lds_u32*)&Vs[0][sflat[i]], 16, 0, 0);
    }
    __syncthreads();
    for (int j = 0; j < 32; ++j) {
        int cur = j & 1;
        if (j < 31) {                                // prefetch next tile -> LDS
            #pragma unroll
            for (int i = 0; i < 2; ++i) {
                __builtin_amdgcn_global_load_lds(
                    (g_u32*)(Kh + (size_t)(j+1)*64*HD + skoff[i]),
                    (lds_u32*)&Ks[cur ^ 1][sflat[i]], 16, 0, 0);
                __builtin_amdgcn_global_load_lds(
                    (g_u32*)(Vh + svoff[i] + (j+1)*64),
                    (lds_u32*)&Vs[cur ^ 1][sflat[i]], 16, 0, 0);
            }
        }
        // ---- QK^T: s[kt] = sum_t mfma32(K[kv=kt*32+l31][d], Q)  (exp2 domain)
        f32x16 s[2] = {};
        #pragma unroll
        for (int kt = 0; kt < 2; ++kt) {
            #pragma unroll
            for (int tt = 0; tt < 4; ++tt) {
                bf16x8 kf = *(const bf16x8*)
                    &Ks[cur][(kt*32 + l31)*64 + ((tt*16 + hi*8) ^ xorv)];
                s[kt] = __builtin_amdgcn_mfma_f32_32x32x16_bf16(
                    kf, qf[tt], s[kt], 0, 0, 0);
            }
        }
        // ---- diagonal mask (wave-uniform trigger; static indices)
        if ((qw0 >> 6) == j) {
            int qrel = (qw0 & 63) + l31;             // lane's q within kv tile
            #pragma unroll
            for (int kt = 0; kt < 2; ++kt)
                #pragma unroll
                for (int r = 0; r < 16; ++r)
                    if (kt*32 + (r&3) + 8*(r>>2) + 4*hi == qrel)
                        s[kt][r] = -1e30f;
        }
        // ---- per-lane softmax over 32 values + pair-combine via lane^32
        float t0[8];
        #pragma unroll
        for (int i = 0; i < 8; ++i)
            t0[i] = fmaxf(fmaxf(s[0][2*i], s[0][2*i+1]),
                          fmaxf(s[1][2*i], s[1][2*i+1]));
        float t1a = fmaxf(fmaxf(t0[0], t0[1]), fmaxf(t0[2], t0[3]));
        float t1b = fmaxf(fmaxf(t0[4], t0[5]), fmaxf(t0[6], t0[7]));
        float mt = fmaxf(t1a, t1b);
        mt = fmaxf(mt, __shfl_xor(mt, 32));
        if (!__all(mt <= m_run + 8.f)) {             // defer-max rescale (rare)
            float mn = fmaxf(m_run, mt);
            float corr = exp2g(m_run - mn);
            m_run = mn;
            l_run *= corr;
            #pragma unroll
            for (int r = 0; r < 16; ++r) {
                float cq = __shfl(corr, (r&3) + 8*(r>>2) + 4*hi);
                o32[0][r] *= cq;
                o32[1][r] *= cq;
            }
        }
        #pragma unroll
        for (int kt = 0; kt < 2; ++kt)
            #pragma unroll
            for (int r = 0; r < 16; ++r)
                s[kt][r] = exp2g(s[kt][r] - m_run);
        // packed-f32 sum tree: 15 v_pk_add_f32 + 1 scalar
        float2 c0[8];
        #pragma unroll
        for (int i = 0; i < 8; ++i)
            c0[i] = pk_add(make_float2(s[0][2*i], s[0][2*i+1]),
                           make_float2(s[1][2*i], s[1][2*i+1]));
        float2 d0 = pk_add(pk_add(c0[0], c0[1]), pk_add(c0[2], c0[3]));
        float2 d1 = pk_add(pk_add(c0[4], c0[5]), pk_add(c0[6], c0[7]));
        float2 e0 = pk_add(d0, d1);
        float rs = e0.x + e0.y;
        rs += __shfl_xor(rs, 32);
        l_run += rs;
        // ---- pack P into PV A-frags (in-register, per ks k-slot of 16 kv)
        #pragma unroll
        for (int ks = 0; ks < 4; ++ks) {
            const int kt = ks >> 1, rb = (ks & 1) * 8;
            unsigned x0 = cvt_pk_bf16(s[kt][rb+0], s[kt][rb+1]);
            unsigned x1 = cvt_pk_bf16(s[kt][rb+2], s[kt][rb+3]);
            unsigned y0 = cvt_pk_bf16(s[kt][rb+4], s[kt][rb+5]);
            unsigned y1 = cvt_pk_bf16(s[kt][rb+6], s[kt][rb+7]);
            asm("v_permlane32_swap_b32 %0, %1" : "+v"(x0), "+v"(y0));
            asm("v_permlane32_swap_b32 %0, %1" : "+v"(x1), "+v"(y1));
            uint4 pw;
            pw.x = x0; pw.y = x1; pw.z = y0; pw.w = y1;
            bf16x8 pa = __builtin_bit_cast(bf16x8, pw);
            #pragma unroll
            for (int dt = 0; dt < 2; ++dt) {
                bf16x8 vb = *(const bf16x8*)
                    &Vs[cur][(dt*32 + l31)*64 + ((ks*16 + hi*8) ^ xorv)];
                o32[dt] = __builtin_amdgcn_mfma_f32_32x32x16_bf16(
                    pa, vb, o32[dt], 0, 0, 0);
            }
        }
        if (j < 31)
            __syncthreads();                         // drains prefetch + dbuf handoff
    }
    float inv = 1.0f / l_run;
    #pragma unroll
    for (int r = 0; r < 16; ++r) {
        int cr = (r&3) + 8*(r>>2) + 4*hi;
        float iv = __shfl(inv, cr);
        int q = qw0 + cr;
        #pragma unroll
        for (int dt = 0; dt < 2; ++dt) {
            int d = dt*32 + l31;
            size_t idx = ((size_t)b * PP + q) * DIM + h * HD + d;
            Oh[idx] = f2bf(o32[dt][r] * iv);
        }
    }
}

// ---------------------------------------------------------------- launch
extern "C" void kernel_launch(void* const* d_in, const int* in_sizes, int n_in,
                              void* d_out, int out_size, void* d_ws, size_t ws_size,
                              hipStream_t stream) {
    const float* x    = (const float*)d_in[0];
    const float* ln_w = (const float*)d_in[1];
    const float* ln_b = (const float*)d_in[2];
    const float* Wq   = (const float*)d_in[3];
    const float* Wk   = (const float*)d_in[4];
    const float* Wv   = (const float*)d_in[5];
    const float* bv   = (const float*)d_in[6];
    const float* Wfc  = (const float*)d_in[7];
    const float* bfc  = (const float*)d_in[8];
    float* out = (float*)d_out;

    char* ws = (char*)d_ws;
    size_t off = 0;
    auto alloc = [&](size_t bytes) {
        void* p = ws + off;
        off += (bytes + 255) & ~(size_t)255;
        return p;
    };
    bf16s* xn     = (bf16s*)alloc((size_t)MTOT * DIM * 2);
    bf16s* Wqkv_t = (bf16s*)alloc((size_t)NQKV * DIM * 2);
    bf16s* Wfc_h  = (bf16s*)alloc((size_t)DIM * DIM * 2);
    bf16s* Qb     = (bf16s*)alloc((size_t)MTOT * DIM * 2);
    bf16s* Kb     = (bf16s*)alloc((size_t)MTOT * DIM * 2);
    bf16s* Vtg    = (bf16s*)alloc((size_t)MTOT * DIM * 2);   // V^T [b,h,d,p]
    bf16s* Ah     = (bf16s*)alloc((size_t)MTOT * DIM * 2);

    const float SC = 0.125f * 1.44269504f;   // softmax scale * log2(e), folded into Wq

    ln_kernel<<<MTOT, 192, 0, stream>>>(x, ln_w, ln_b, xn);

    transpose_all<<<dim3(24, 24, 4), dim3(32, 8), 0, stream>>>(
        Wq, Wk, Wv, Wfc, Wqkv_t, Wfc_h, SC);

    gemm_bt<0><<<(MTOT / 128) * (NQKV / 128), 256, 0, stream>>>(
        xn, Wqkv_t, bv, Qb, Kb, Vtg, nullptr);

    attn_kernel<<<BB * HEADS * (PP / QBLK), 256, 0, stream>>>(Qb, Kb, Vtg, Ah);

    gemm_bt<1><<<(MTOT / 128) * (DIM / 64), 256, 0, stream>>>(
        Ah, Wfc_h, bfc, nullptr, nullptr, nullptr, out);
}

// Round 24
// 154.942 us; speedup vs baseline: 1.0732x; 1.0096x over previous
//
#include <hip/hip_runtime.h>

#define DIM    768
#define HEADS  12
#define HD     64
#define BB     4
#define PP     2048
#define MTOT   8192   /* BB*PP */
#define NQKV   2304
#define QBLK   128

typedef unsigned short bf16s;                                   // bf16 storage
typedef short bf16x8 __attribute__((ext_vector_type(8)));       // MFMA A/B frag
typedef float f32x4  __attribute__((ext_vector_type(4)));       // 16x16 C/D
typedef float f32x16 __attribute__((ext_vector_type(16)));      // 32x32 C/D

typedef const __attribute__((address_space(1))) unsigned int g_u32;
typedef __attribute__((address_space(3))) unsigned int lds_u32;

__device__ __forceinline__ bf16s f2bf(float f) {
    unsigned int u = __float_as_uint(f);
    unsigned int r = u + 0x7fffu + ((u >> 16) & 1u);            // RNE
    return (bf16s)(r >> 16);
}
__device__ __forceinline__ float bf2f(bf16s s) {
    return __uint_as_float(((unsigned int)s) << 16);
}
__device__ __forceinline__ float exp2g(float x) {
    return __builtin_amdgcn_exp2f(x);                           // v_exp_f32
}
__device__ __forceinline__ unsigned cvt_pk_bf16(float a, float b) {
    unsigned r;
    asm("v_cvt_pk_bf16_f32 %0, %1, %2" : "=v"(r) : "v"(a), "v"(b));
    return r;                                                   // lo=bf16(a), hi=bf16(b)
}
__device__ __forceinline__ float2 pk_add(float2 a, float2 b) {
    float2 r;
    asm("v_pk_add_f32 %0, %1, %2" : "=v"(r) : "v"(a), "v"(b));
    return r;
}

// ------------------------------------------- fused LayerNorm + weight prep
// grid = MTOT (LN, 192 active of 256 thr) ++ 24*24*4 (transpose tiles)
// LN: row -> xn bf16. Transpose: z 0=Wq(*sc) 1=Wk 2=Wv -> Wqkv_t; 3=Wfc -> Wfc_h
__global__ __launch_bounds__(256) void prep_kernel(
        const float* __restrict__ x, const float* __restrict__ w,
        const float* __restrict__ b, bf16s* __restrict__ xn,
        const float* __restrict__ Wq, const float* __restrict__ Wk,
        const float* __restrict__ Wv, const float* __restrict__ Wfc,
        bf16s* __restrict__ Wqkv_t, bf16s* __restrict__ Wfc_h, float sc) {
    __shared__ float shbuf[32 * 33];                 // tile (transpose) / red (LN)
    int bid = blockIdx.x;
    int t = threadIdx.x;
    if (bid < MTOT) {
        // ---------------- LayerNorm (192 active threads, float4 loads)
        float* red = shbuf;
        const float* xr = x + (size_t)bid * DIM;
        float4 v = make_float4(0.f, 0.f, 0.f, 0.f);
        float s = 0.f, ss = 0.f;
        if (t < 192) {
            v  = *(const float4*)&xr[t*4];
            s  = (v.x + v.y) + (v.z + v.w);
            ss = (v.x*v.x + v.y*v.y) + (v.z*v.z + v.w*v.w);
        }
        for (int off = 32; off; off >>= 1) {
            s  += __shfl_down(s, off);
            ss += __shfl_down(ss, off);
        }
        int wid = t >> 6, lane = t & 63;
        if (lane == 0 && wid < 3) { red[wid] = s; red[4 + wid] = ss; }
        __syncthreads();
        if (t == 0) {
            float S  = red[0] + red[1] + red[2];
            float SS = red[4] + red[5] + red[6];
            float mean = S * (1.0f / DIM);
            float var  = SS * (1.0f / DIM) - mean * mean;
            red[0] = mean;
            red[1] = rsqrtf(var + 1e-5f);
        }
        __syncthreads();
        if (t < 192) {
            float mean = red[0], inv = red[1];
            float4 wv = *(const float4*)&w[t*4];
            float4 bv = *(const float4*)&b[t*4];
            uint2 pk;
            pk.x = cvt_pk_bf16((v.x - mean) * inv * wv.x + bv.x,
                               (v.y - mean) * inv * wv.y + bv.y);
            pk.y = cvt_pk_bf16((v.z - mean) * inv * wv.z + bv.z,
                               (v.w - mean) * inv * wv.w + bv.w);
            *(uint2*)&xn[(size_t)bid * DIM + t*4] = pk;
        }
    } else {
        // ---------------- weight transpose+cast (32x32 tile per block)
        float (*tile)[33] = (float(*)[33])shbuf;
        int tb = bid - MTOT;
        int z  = tb / 576;
        int rem = tb % 576;
        int n0 = (rem % 24) * 32, k0 = (rem / 24) * 32;
        const float* src = (z == 0) ? Wq : (z == 1) ? Wk : (z == 2) ? Wv : Wfc;
        float scale = (z == 0) ? sc : 1.0f;
        int tx = t & 31, ty = t >> 5;
        #pragma unroll
        for (int i = 0; i < 4; ++i)
            tile[ty + 8*i][tx] = src[(size_t)(k0 + ty + 8*i) * DIM + n0 + tx];
        __syncthreads();
        #pragma unroll
        for (int i = 0; i < 4; ++i) {
            float v = tile[tx][ty + 8*i] * scale;
            size_t oidx = (size_t)(n0 + ty + 8*i) * DIM + k0 + tx;
            bf16s hi = f2bf(v);
            if (z < 3) Wqkv_t[(size_t)z * DIM * DIM + oidx] = hi;
            else       Wfc_h[oidx] = hi;
        }
    }
}

// ----------------------------------------------------------------- GEMM
// C[M x N] = A[M x 768(K)] @ Bt[N x 768]^T ; 4 waves
// MODE 0: 128x128 tile, N=2304. Q/K region: SWAPPED operands (acc = C^T) so
//   each lane holds 4 d-consecutive values -> packed uint2 [p][d] stores.
//   V region: unswapped, packed V^T [d][p] stores (+bv).
// MODE 1: 128x64 tile, N=768, K=768, fp32 out + bfc
// Staging: global_load_lds width=16, linear LDS, source-XOR swizzle + read-XOR.
template<int MODE>
__global__ __launch_bounds__(256) void gemm_bt(
        const bf16s* __restrict__ A0, const bf16s* __restrict__ B0,
        const float* __restrict__ bias,
        bf16s* __restrict__ Qo, bf16s* __restrict__ Ko, bf16s* __restrict__ Vo,
        float* __restrict__ out) {
    const int BN   = (MODE == 0 ? 128 : 64);
    const int NI   = (MODE == 0 ? 4 : 2);             // B frags per wave
    const int BISS = (MODE == 0 ? 4 : 2);             // B staging issues
    const int NT   = (MODE == 0 ? NQKV / 128 : DIM / 64);
    const int NWG  = (MTOT / 128) * NT;
    int bid = blockIdx.x;
    bid = (bid & 7) * (NWG / 8) + (bid >> 3);         // XCD swizzle (NWG%8==0)
    int nt = bid % NT, mt = bid / NT;
    int m0 = mt * 128, n0 = nt * BN;
    __shared__ bf16s As[128 * 64];
    __shared__ bf16s Bs[BN * 64];
    int t = threadIdx.x;
    int lane = t & 63, w = t >> 6;
    int wr = w >> 1, wc = w & 1;
    int lr = lane & 15, lg = lane >> 4;
    const bool swp = (MODE == 0) && (n0 < 2 * DIM);   // Q/K region: C^T layout
    // staging geometry: thread t, issue i covers LDS elems [i*2048+t*8, +8)
    int sflat[4];
    size_t sgoff[4];
    #pragma unroll
    for (int i = 0; i < 4; ++i) {
        int flat = i * 2048 + t * 8;
        int r = flat >> 6, c = flat & 63;
        int csw = (((c >> 3) ^ (r & 7)) << 3);        // source-side swizzle
        sflat[i] = flat;
        sgoff[i] = (size_t)r * DIM + csw;             // + m0/n0*DIM + k0 later
    }
    const int xorv = (lr & 7) << 3;                   // read-side XOR (elems)
    f32x4 acc[4][NI] = {};
    const int KI = DIM / 64;
    for (int it = 0; it < KI; ++it) {
        int k0 = it * 64;
        #pragma unroll
        for (int i = 0; i < 4; ++i)
            __builtin_amdgcn_global_load_lds(
                (g_u32*)(A0 + (size_t)m0 * DIM + k0 + sgoff[i]),
                (lds_u32*)&As[sflat[i]], 16, 0, 0);
        #pragma unroll
        for (int i = 0; i < BISS; ++i)
            __builtin_amdgcn_global_load_lds(
                (g_u32*)(B0 + (size_t)n0 * DIM + k0 + sgoff[i]),
                (lds_u32*)&Bs[sflat[i]], 16, 0, 0);
        __syncthreads();                               // vmcnt(0) drain + barrier
        #pragma unroll
        for (int kk = 0; kk < 2; ++kk) {
            bf16x8 af[4], bfr[NI];
            #pragma unroll
            for (int i = 0; i < 4; ++i) {
                int arow = wr*64 + i*16 + lr;
                af[i] = *(const bf16x8*)&As[arow*64 + ((kk*32 + lg*8) ^ xorv)];
            }
            #pragma unroll
            for (int i = 0; i < NI; ++i) {
                int brow = wc*(BN/2) + i*16 + lr;
                bfr[i] = *(const bf16x8*)&Bs[brow*64 + ((kk*32 + lg*8) ^ xorv)];
            }
            if (swp) {                                 // block-uniform branch
                #pragma unroll
                for (int mi = 0; mi < 4; ++mi)
                    #pragma unroll
                    for (int ni = 0; ni < NI; ++ni)
                        acc[mi][ni] = __builtin_amdgcn_mfma_f32_16x16x32_bf16(
                            bfr[ni], af[mi], acc[mi][ni], 0, 0, 0);
            } else {
                #pragma unroll
                for (int mi = 0; mi < 4; ++mi)
                    #pragma unroll
                    for (int ni = 0; ni < NI; ++ni)
                        acc[mi][ni] = __builtin_amdgcn_mfma_f32_16x16x32_bf16(
                            af[mi], bfr[ni], acc[mi][ni], 0, 0, 0);
            }
        }
        __syncthreads();
    }
    if (MODE == 0) {
        if (swp) {
            // C^T: lane holds m = ...+lr (fixed), n = ...+lg*4+r (4 consecutive d)
            bf16s* dst = (n0 >= DIM) ? Ko : Qo;
            int nbase = n0 - ((n0 >= DIM) ? DIM : 0);
            #pragma unroll
            for (int mi = 0; mi < 4; ++mi) {
                int m = m0 + wr*64 + mi*16 + lr;
                int b = m >> 11, p = m & 2047;
                #pragma unroll
                for (int ni = 0; ni < NI; ++ni) {
                    int nb = nbase + wc*64 + ni*16 + lg*4;
                    int hh = nb >> 6, d0 = nb & 63;
                    uint2 pk;
                    pk.x = cvt_pk_bf16(acc[mi][ni][0], acc[mi][ni][1]);
                    pk.y = cvt_pk_bf16(acc[mi][ni][2], acc[mi][ni][3]);
                    *(uint2*)&dst[(((size_t)(b*HEADS + hh))*PP + p)*HD + d0] = pk;
                }
            }
        } else {
            // V region: lane holds n = ...+lr (fixed d), m = ...+lg*4+r (4 consec p)
            #pragma unroll
            for (int mi = 0; mi < 4; ++mi) {
                int m_base = m0 + wr*64 + mi*16 + lg*4;
                int b = m_base >> 11, p = m_base & 2047;
                #pragma unroll
                for (int ni = 0; ni < NI; ++ni) {
                    int n = n0 + wc*64 + ni*16 + lr;
                    int within = n - 2*DIM;
                    int hh = within >> 6, d = within & 63;
                    float bb = bias[within];
                    uint2 pk;
                    pk.x = cvt_pk_bf16(acc[mi][ni][0] + bb, acc[mi][ni][1] + bb);
                    pk.y = cvt_pk_bf16(acc[mi][ni][2] + bb, acc[mi][ni][3] + bb);
                    *(uint2*)&Vo[(((size_t)(b*HEADS + hh))*HD + d)*PP + p] = pk;
                }
            }
        }
    } else {
        #pragma unroll
        for (int mi = 0; mi < 4; ++mi)
            #pragma unroll
            for (int ni = 0; ni < NI; ++ni)
                #pragma unroll
                for (int r = 0; r < 4; ++r) {
                    int m = m0 + wr*64 + mi*16 + lg*4 + r;
                    int n = n0 + wc*32 + ni*16 + lr;
                    out[(size_t)m * DIM + n] = acc[mi][ni][r] + bias[n];
                }
    }
}

// ------------------------------------------------------------ attention
// 32x32 MFMA structure (R15/R20-proven): block = (b,h,qtile-of-128); 4 waves.
// Swapped QK^T = mfma32(K, Q): C col=lane&31=q, row=crow(r,hi)=(r&3)+8(r>>2)+4hi.
// Softmax per-lane; pair-combine via shfl_xor 32; pk_add sum tree.
// P -> PV A-frags in-register: 16 cvt_pk + 8 v_permlane32_swap_b32.
// K/V via global_load_lds (linear LDS, src-XOR swizzle); 2-buffer dbuf,
// ONE __syncthreads per 64-kv iter. Output: single bf16.
__global__ __launch_bounds__(256, 3) void attn_kernel(
        const bf16s* __restrict__ Q, const bf16s* __restrict__ K,
        const bf16s* __restrict__ Vt,
        bf16s* __restrict__ Oh) {
    const int NWG = BB * HEADS * (PP / QBLK);        // 768
    int orig = blockIdx.x;
    int wg = (orig & 7) * (NWG / 8) + (orig >> 3);   // XCD swizzle
    int qt  = wg & 15;
    int tmp = wg >> 4;
    int h   = tmp % HEADS;
    int b   = tmp / HEADS;
    const size_t headoff = ((size_t)(b * HEADS + h)) * PP * HD;
    const bf16s* Qh = Q  + headoff;
    const bf16s* Kh = K  + headoff;
    const bf16s* Vh = Vt + headoff;                  // [d][p]
    __shared__ bf16s Ks[2][64 * 64];                 // [kv][d], swizzled
    __shared__ bf16s Vs[2][64 * 64];                 // [d][kv], swizzled
    int t = threadIdx.x, lane = t & 63, w = t >> 6;
    int l31 = lane & 31, hi = lane >> 5;
    int q0  = qt * QBLK;
    int qw0 = q0 + w * 32;                           // wave's 32 q rows
    const int xorv = (l31 & 7) << 3;                 // read-side XOR (elems)
    // Q fragments (B-operand): lane holds Q[qw0+l31][tt*16 + hi*8 + e]
    bf16x8 qf[4];
    #pragma unroll
    for (int tt = 0; tt < 4; ++tt)
        qf[tt] = *(const bf16x8*)&Qh[(size_t)(qw0 + l31) * HD + tt*16 + hi*8];
    float m_run = -1e30f, l_run = 0.f;
    f32x16 o32[2] = {};                              // O[q=crow(r,hi)][d=dt*32+l31]
    // staging geometry: thread t, issue i covers LDS elems [i*2048+t*8, +8)
    int sflat[2];
    size_t skoff[2], svoff[2];
    #pragma unroll
    for (int i = 0; i < 2; ++i) {
        int flat = i * 2048 + t * 8;
        int r = flat >> 6, c = flat & 63;
        int csw = (((c >> 3) ^ (r & 7)) << 3);       // source-side swizzle
        sflat[i] = flat;
        skoff[i] = (size_t)r * HD + csw;             // + j*64*HD per tile
        svoff[i] = (size_t)r * PP + csw;             // + j*64 per tile
    }
    #pragma unroll
    for (int i = 0; i < 2; ++i) {
        __builtin_amdgcn_global_load_lds((g_u32*)(Kh + skoff[i]),
                                         (lds_u32*)&Ks[0][sflat[i]], 16, 0, 0);
        __builtin_amdgcn_global_load_lds((g_u32*)(Vh + svoff[i]),
                                         (lds_u32*)&Vs[0][sflat[i]], 16, 0, 0);
    }
    __syncthreads();
    for (int j = 0; j < 32; ++j) {
        int cur = j & 1;
        if (j < 31) {                                // prefetch next tile -> LDS
            #pragma unroll
            for (int i = 0; i < 2; ++i) {
                __builtin_amdgcn_global_load_lds(
                    (g_u32*)(Kh + (size_t)(j+1)*64*HD + skoff[i]),
                    (lds_u32*)&Ks[cur ^ 1][sflat[i]], 16, 0, 0);
                __builtin_amdgcn_global_load_lds(
                    (g_u32*)(Vh + svoff[i] + (j+1)*64),
                    (lds_u32*)&Vs[cur ^ 1][sflat[i]], 16, 0, 0);
            }
        }
        // ---- QK^T: s[kt] = sum_t mfma32(K[kv=kt*32+l31][d], Q)  (exp2 domain)
        f32x16 s[2] = {};
        #pragma unroll
        for (int kt = 0; kt < 2; ++kt) {
            #pragma unroll
            for (int tt = 0; tt < 4; ++tt) {
                bf16x8 kf = *(const bf16x8*)
                    &Ks[cur][(kt*32 + l31)*64 + ((tt*16 + hi*8) ^ xorv)];
                s[kt] = __builtin_amdgcn_mfma_f32_32x32x16_bf16(
                    kf, qf[tt], s[kt], 0, 0, 0);
            }
        }
        // ---- diagonal mask (wave-uniform trigger; static indices)
        if ((qw0 >> 6) == j) {
            int qrel = (qw0 & 63) + l31;             // lane's q within kv tile
            #pragma unroll
            for (int kt = 0; kt < 2; ++kt)
                #pragma unroll
                for (int r = 0; r < 16; ++r)
                    if (kt*32 + (r&3) + 8*(r>>2) + 4*hi == qrel)
                        s[kt][r] = -1e30f;
        }
        // ---- per-lane softmax over 32 values + pair-combine via lane^32
        float t0[8];
        #pragma unroll
        for (int i = 0; i < 8; ++i)
            t0[i] = fmaxf(fmaxf(s[0][2*i], s[0][2*i+1]),
                          fmaxf(s[1][2*i], s[1][2*i+1]));
        float t1a = fmaxf(fmaxf(t0[0], t0[1]), fmaxf(t0[2], t0[3]));
        float t1b = fmaxf(fmaxf(t0[4], t0[5]), fmaxf(t0[6], t0[7]));
        float mt = fmaxf(t1a, t1b);
        mt = fmaxf(mt, __shfl_xor(mt, 32));
        if (!__all(mt <= m_run + 8.f)) {             // defer-max rescale (rare)
            float mn = fmaxf(m_run, mt);
            float corr = exp2g(m_run - mn);
            m_run = mn;
            l_run *= corr;
            #pragma unroll
            for (int r = 0; r < 16; ++r) {
                float cq = __shfl(corr, (r&3) + 8*(r>>2) + 4*hi);
                o32[0][r] *= cq;
                o32[1][r] *= cq;
            }
        }
        #pragma unroll
        for (int kt = 0; kt < 2; ++kt)
            #pragma unroll
            for (int r = 0; r < 16; ++r)
                s[kt][r] = exp2g(s[kt][r] - m_run);
        // packed-f32 sum tree: 15 v_pk_add_f32 + 1 scalar
        float2 c0[8];
        #pragma unroll
        for (int i = 0; i < 8; ++i)
            c0[i] = pk_add(make_float2(s[0][2*i], s[0][2*i+1]),
                           make_float2(s[1][2*i], s[1][2*i+1]));
        float2 d0 = pk_add(pk_add(c0[0], c0[1]), pk_add(c0[2], c0[3]));
        float2 d1 = pk_add(pk_add(c0[4], c0[5]), pk_add(c0[6], c0[7]));
        float2 e0 = pk_add(d0, d1);
        float rs = e0.x + e0.y;
        rs += __shfl_xor(rs, 32);
        l_run += rs;
        // ---- pack P into PV A-frags (in-register, per ks k-slot of 16 kv)
        #pragma unroll
        for (int ks = 0; ks < 4; ++ks) {
            const int kt = ks >> 1, rb = (ks & 1) * 8;
            unsigned x0 = cvt_pk_bf16(s[kt][rb+0], s[kt][rb+1]);
            unsigned x1 = cvt_pk_bf16(s[kt][rb+2], s[kt][rb+3]);
            unsigned y0 = cvt_pk_bf16(s[kt][rb+4], s[kt][rb+5]);
            unsigned y1 = cvt_pk_bf16(s[kt][rb+6], s[kt][rb+7]);
            asm("v_permlane32_swap_b32 %0, %1" : "+v"(x0), "+v"(y0));
            asm("v_permlane32_swap_b32 %0, %1" : "+v"(x1), "+v"(y1));
            uint4 pw;
            pw.x = x0; pw.y = x1; pw.z = y0; pw.w = y1;
            bf16x8 pa = __builtin_bit_cast(bf16x8, pw);
            #pragma unroll
            for (int dt = 0; dt < 2; ++dt) {
                bf16x8 vb = *(const bf16x8*)
                    &Vs[cur][(dt*32 + l31)*64 + ((ks*16 + hi*8) ^ xorv)];
                o32[dt] = __builtin_amdgcn_mfma_f32_32x32x16_bf16(
                    pa, vb, o32[dt], 0, 0, 0);
            }
        }
        if (j < 31)
            __syncthreads();                         // drains prefetch + dbuf handoff
    }
    float inv = 1.0f / l_run;
    #pragma unroll
    for (int r = 0; r < 16; ++r) {
        int cr = (r&3) + 8*(r>>2) + 4*hi;
        float iv = __shfl(inv, cr);
        int q = qw0 + cr;
        #pragma unroll
        for (int dt = 0; dt < 2; ++dt) {
            int d = dt*32 + l31;
            size_t idx = ((size_t)b * PP + q) * DIM + h * HD + d;
            Oh[idx] = f2bf(o32[dt][r] * iv);
        }
    }
}

// ---------------------------------------------------------------- launch
extern "C" void kernel_launch(void* const* d_in, const int* in_sizes, int n_in,
                              void* d_out, int out_size, void* d_ws, size_t ws_size,
                              hipStream_t stream) {
    const float* x    = (const float*)d_in[0];
    const float* ln_w = (const float*)d_in[1];
    const float* ln_b = (const float*)d_in[2];
    const float* Wq   = (const float*)d_in[3];
    const float* Wk   = (const float*)d_in[4];
    const float* Wv   = (const float*)d_in[5];
    const float* bv   = (const float*)d_in[6];
    const float* Wfc  = (const float*)d_in[7];
    const float* bfc  = (const float*)d_in[8];
    float* out = (float*)d_out;

    char* ws = (char*)d_ws;
    size_t off = 0;
    auto alloc = [&](size_t bytes) {
        void* p = ws + off;
        off += (bytes + 255) & ~(size_t)255;
        return p;
    };
    bf16s* xn     = (bf16s*)alloc((size_t)MTOT * DIM * 2);
    bf16s* Wqkv_t = (bf16s*)alloc((size_t)NQKV * DIM * 2);
    bf16s* Wfc_h  = (bf16s*)alloc((size_t)DIM * DIM * 2);
    bf16s* Qb     = (bf16s*)alloc((size_t)MTOT * DIM * 2);
    bf16s* Kb     = (bf16s*)alloc((size_t)MTOT * DIM * 2);
    bf16s* Vtg    = (bf16s*)alloc((size_t)MTOT * DIM * 2);   // V^T [b,h,d,p]
    bf16s* Ah     = (bf16s*)alloc((size_t)MTOT * DIM * 2);

    const float SC = 0.125f * 1.44269504f;   // softmax scale * log2(e), folded into Wq

    prep_kernel<<<MTOT + 24 * 24 * 4, 256, 0, stream>>>(
        x, ln_w, ln_b, xn, Wq, Wk, Wv, Wfc, Wqkv_t, Wfc_h, SC);

    gemm_bt<0><<<(MTOT / 128) * (NQKV / 128), 256, 0, stream>>>(
        xn, Wqkv_t, bv, Qb, Kb, Vtg, nullptr);

    attn_kernel<<<BB * HEADS * (PP / QBLK), 256, 0, stream>>>(Qb, Kb, Vtg, Ah);

    gemm_bt<1><<<(MTOT / 128) * (DIM / 64), 256, 0, stream>>>(
        Ah, Wfc_h, bfc, nullptr, nullptr, nullptr, out);
}